// Round 1
// baseline (632.936 us; speedup 1.0000x reference)
//
#include <hip/hip_runtime.h>
#include <hip/hip_bf16.h>
#include <math.h>

typedef __attribute__((ext_vector_type(8))) short short8;
typedef __attribute__((ext_vector_type(4))) float f32x4;

static __device__ __forceinline__ unsigned short f2bf(float f) {
    union { float f; unsigned u; } a; a.f = f;
    unsigned r = a.u + 0x7FFFu + ((a.u >> 16) & 1u);   // round-to-nearest-even
    return (unsigned short)(r >> 16);
}
static __device__ __forceinline__ float bf2f(unsigned short h) {
    union { float f; unsigned u; } a; a.u = ((unsigned)h) << 16; return a.f;
}
static __device__ __forceinline__ float sigmoidf_(float x) {
    return 1.0f / (1.0f + expf(-x));
}

// C[m][n] = sum_k A[m][k] * Bw[n][k]  (+ bias[n]), optional sigmoid epilogue.
// A: [M][K] fp32 row-major, Bw: [N][K] fp32 row-major (B-transposed layout).
// Split-bf16: each fp32 -> hi + lo bf16; a*b ~= ah*bh + ah*bl + al*bh.
template <int EPI>
__launch_bounds__(256, 2)
__global__ void gemm_bt_split(const float* __restrict__ A,
                              const float* __restrict__ Bw,
                              const float* __restrict__ bias,
                              float* __restrict__ C,
                              int M, int N, int K)
{
    constexpr int BM = 128, BN = 128, BK = 32;
    constexpr int PK = 40;   // padded LDS row (bf16 elems): 80B stride -> 2-way bank alias (free)

    __shared__ unsigned short Ah[BM * PK];
    __shared__ unsigned short Al[BM * PK];
    __shared__ unsigned short Bh[BN * PK];
    __shared__ unsigned short Bl[BN * PK];

    const int tid  = threadIdx.x;
    const int lane = tid & 63;
    const int wid  = tid >> 6;       // 4 waves
    const int wr   = wid >> 1;       // wave row (0..1) -> 64 rows
    const int wc   = wid & 1;        // wave col (0..1) -> 64 cols

    const int brow = blockIdx.y * BM;
    const int bcol = blockIdx.x * BN;

    f32x4 acc[4][4] = {};

    // staging: each thread loads 16 fp32 of A and 16 of B per K-step
    const int trow = tid >> 1;            // 0..127
    const int tcol = (tid & 1) * 16;      // 0 or 16
    const float* ga = A  + (size_t)(brow + trow) * K + tcol;
    const float* gb = Bw + (size_t)(bcol + trow) * K + tcol;

    const int lr = lane & 15;             // fragment row
    const int kb = (lane >> 4) * 8;       // fragment k-base

    for (int k0 = 0; k0 < K; k0 += BK) {
        __syncthreads();
#pragma unroll
        for (int i = 0; i < 4; ++i) {
            float4 va = *(const float4*)(ga + k0 + 4 * i);
            float4 vb = *(const float4*)(gb + k0 + 4 * i);
            ushort4 ha, la, hb, lb;
            ha.x = f2bf(va.x); la.x = f2bf(va.x - bf2f(ha.x));
            ha.y = f2bf(va.y); la.y = f2bf(va.y - bf2f(ha.y));
            ha.z = f2bf(va.z); la.z = f2bf(va.z - bf2f(ha.z));
            ha.w = f2bf(va.w); la.w = f2bf(va.w - bf2f(ha.w));
            hb.x = f2bf(vb.x); lb.x = f2bf(vb.x - bf2f(hb.x));
            hb.y = f2bf(vb.y); lb.y = f2bf(vb.y - bf2f(hb.y));
            hb.z = f2bf(vb.z); lb.z = f2bf(vb.z - bf2f(hb.z));
            hb.w = f2bf(vb.w); lb.w = f2bf(vb.w - bf2f(hb.w));
            const int off = trow * PK + tcol + 4 * i;
            *(ushort4*)&Ah[off] = ha;
            *(ushort4*)&Al[off] = la;
            *(ushort4*)&Bh[off] = hb;
            *(ushort4*)&Bl[off] = lb;
        }
        __syncthreads();

        short8 ah[4], al[4];
#pragma unroll
        for (int m = 0; m < 4; ++m) {
            const int r = (wr * 64 + m * 16 + lr) * PK + kb;
            ah[m] = *(const short8*)&Ah[r];
            al[m] = *(const short8*)&Al[r];
        }
#pragma unroll
        for (int n = 0; n < 4; ++n) {
            const int r = (wc * 64 + n * 16 + lr) * PK + kb;
            short8 bh = *(const short8*)&Bh[r];
            short8 bl = *(const short8*)&Bl[r];
#pragma unroll
            for (int m = 0; m < 4; ++m) {
                acc[m][n] = __builtin_amdgcn_mfma_f32_16x16x32_bf16(ah[m], bh, acc[m][n], 0, 0, 0);
                acc[m][n] = __builtin_amdgcn_mfma_f32_16x16x32_bf16(ah[m], bl, acc[m][n], 0, 0, 0);
                acc[m][n] = __builtin_amdgcn_mfma_f32_16x16x32_bf16(al[m], bh, acc[m][n], 0, 0, 0);
            }
        }
    }

    // epilogue: C row = (lane>>4)*4 + j, col = lane&15 within each 16x16 fragment
#pragma unroll
    for (int m = 0; m < 4; ++m) {
        const int row = brow + wr * 64 + m * 16 + (lane >> 4) * 4;
#pragma unroll
        for (int n = 0; n < 4; ++n) {
            const int col = bcol + wc * 64 + n * 16 + (lane & 15);
            const float bv = bias[col];
#pragma unroll
            for (int j = 0; j < 4; ++j) {
                float v = acc[m][n][j] + bv;
                if (EPI == 1) v = sigmoidf_(v);
                C[(size_t)(row + j) * N + col] = v;
            }
        }
    }
}

// GRU gate with h=0: r=sig(i_r+h_r), z=sig(i_z+h_z), n=tanh(i_n+r*h_n), h_new=(1-z)*n
__global__ void gate_kernel(const float* __restrict__ gi,
                            const float* __restrict__ b_hh,
                            float* __restrict__ hnew, int B, int H)
{
    const int H4 = H >> 2;
    const int i = blockIdx.x * blockDim.x + threadIdx.x;
    if (i >= B * H4) return;
    const int b = i / H4;
    const int h4 = (i - b * H4) * 4;
    const size_t base = (size_t)b * 3 * H;
    float4 ir = *(const float4*)(gi + base + h4);
    float4 iz = *(const float4*)(gi + base + H + h4);
    float4 in4 = *(const float4*)(gi + base + 2 * H + h4);
    float4 hr = *(const float4*)(b_hh + h4);
    float4 hz = *(const float4*)(b_hh + H + h4);
    float4 hn = *(const float4*)(b_hh + 2 * H + h4);
    float4 o;
    {
        float r = sigmoidf_(ir.x + hr.x), z = sigmoidf_(iz.x + hz.x);
        o.x = (1.0f - z) * tanhf(in4.x + r * hn.x);
    }
    {
        float r = sigmoidf_(ir.y + hr.y), z = sigmoidf_(iz.y + hz.y);
        o.y = (1.0f - z) * tanhf(in4.y + r * hn.y);
    }
    {
        float r = sigmoidf_(ir.z + hr.z), z = sigmoidf_(iz.z + hz.z);
        o.z = (1.0f - z) * tanhf(in4.z + r * hn.z);
    }
    {
        float r = sigmoidf_(ir.w + hr.w), z = sigmoidf_(iz.w + hz.w);
        o.w = (1.0f - z) * tanhf(in4.w + r * hn.w);
    }
    *(float4*)(hnew + (size_t)b * H + h4) = o;
}

// out[b][o][t] = res[b][o] for t in [0,T). Flat, fully coalesced writes.
__global__ void bcast_kernel(const float* __restrict__ res,
                             float* __restrict__ out, int BO, int T)
{
    const int bo0 = blockIdx.x * 256;
    if (T & 1) {
        float* op = out + (size_t)bo0 * T;
        const int n = 256 * T;
        for (int j = threadIdx.x; j < n; j += blockDim.x)
            op[j] = res[bo0 + j / T];
    } else {
        const int half = T >> 1;
        float2* o2 = (float2*)(out + (size_t)bo0 * T);
        const int n2 = 256 * half;
        for (int j = threadIdx.x; j < n2; j += blockDim.x) {
            const float v = res[bo0 + j / half];
            o2[j] = make_float2(v, v);
        }
    }
}

extern "C" void kernel_launch(void* const* d_in, const int* in_sizes, int n_in,
                              void* d_out, int out_size, void* d_ws, size_t ws_size,
                              hipStream_t stream)
{
    const float* x     = (const float*)d_in[0];
    const float* w_ih  = (const float*)d_in[1];
    // d_in[2] = w_hh: provably unused (hidden state stays 0)
    const float* b_ih  = (const float*)d_in[3];
    const float* b_hh  = (const float*)d_in[4];
    const float* w_cls = (const float*)d_in[5];
    const float* b_cls = (const float*)d_in[6];

    const int H3 = in_sizes[3];          // 3H = 6144
    const int H  = H3 / 3;               // 2048
    const int I  = in_sizes[1] / H3;     // 2048
    const int B  = in_sizes[0] / I;      // 1024
    const int O  = in_sizes[6];          // 2048
    const int T  = out_size / (B * O);   // 30

    float* gi   = (float*)d_ws;                    // [B][3H]
    float* hnew = gi + (size_t)B * H3;             // [B][H]
    float* res  = hnew + (size_t)B * H;            // [B][O]
    float* out  = (float*)d_out;

    dim3 blk(256);

    // GEMM1: gi = x @ w_ih^T + b_ih   (M=B, N=3H, K=I)
    gemm_bt_split<0><<<dim3(H3 / 128, B / 128), blk, 0, stream>>>(x, w_ih, b_ih, gi, B, H3, I);

    // gate: h_new
    {
        const int tot = B * H / 4;
        gate_kernel<<<(tot + 255) / 256, blk, 0, stream>>>(gi, b_hh, hnew, B, H);
    }

    // GEMM2: res = sigmoid(h_new @ w_cls^T + b_cls)   (M=B, N=O, K=H)
    gemm_bt_split<1><<<dim3(O / 128, B / 128), blk, 0, stream>>>(hnew, w_cls, b_cls, res, B, O, H);

    // broadcast across T
    bcast_kernel<<<(B * O) / 256, blk, 0, stream>>>(res, out, B * O, T);
}

// Round 2
// 408.944 us; speedup vs baseline: 1.5477x; 1.5477x over previous
//
#include <hip/hip_runtime.h>
#include <hip/hip_bf16.h>
#include <math.h>

typedef __attribute__((ext_vector_type(8))) _Float16 f16x8;
typedef __attribute__((ext_vector_type(4))) float f32x4;

static __device__ __forceinline__ float sigmoidf_(float x) {
    return 1.0f / (1.0f + expf(-x));
}

// ---------------------------------------------------------------------------
// fp32 -> fp16 conversion with chunk-XOR pre-swizzle.
// Logical element src[row][kc*8+j] lands at dst[row][kcs*8+j] where
// kcs = (kc & ~7) | ((kc&7) ^ (row&7)).  GEMM stages LDS linearly via
// global_load_lds, so the LDS tile ends up XOR-swizzled; ds_read applies the
// same XOR -> conflict-free b128 fragment reads (rule #21: both-sides).
// ---------------------------------------------------------------------------
__global__ void cvt_swz(const float* __restrict__ src, _Float16* __restrict__ dst,
                        int nchunks, int ck)
{
    const int c = blockIdx.x * 256 + threadIdx.x;
    if (c >= nchunks) return;
    const int row = c / ck;
    const int kc  = c - row * ck;
    const int kcs = (kc & ~7) | ((kc & 7) ^ (row & 7));
    const float* s = src + (size_t)c * 8;
    float4 v0 = *(const float4*)s;
    float4 v1 = *(const float4*)(s + 4);
    f16x8 h;
    h[0] = (_Float16)v0.x; h[1] = (_Float16)v0.y;
    h[2] = (_Float16)v0.z; h[3] = (_Float16)v0.w;
    h[4] = (_Float16)v1.x; h[5] = (_Float16)v1.y;
    h[6] = (_Float16)v1.z; h[7] = (_Float16)v1.w;
    *(f16x8*)(dst + (size_t)row * ((size_t)ck * 8) + (size_t)kcs * 8) = h;
}

// ---------------------------------------------------------------------------
// C[m][n] = sum_k A[m][k]*Bw[n][k] + bias[n], optional sigmoid.
// A: [M][K] fp16 (pre-swizzled), Bw: [N][K] fp16 (pre-swizzled).
// m97-style: global_load_lds width-16 staging, 2 barriers/K-step, BK=64,
// 4 waves in a 2x2 grid, each wave (BM/2)x(BN/2) via 16x16x32 f16 MFMA.
// ---------------------------------------------------------------------------
template <int BM, int BN, int EPI>
__launch_bounds__(256, 3)
__global__ void gemm16(const _Float16* __restrict__ A, const _Float16* __restrict__ Bw,
                       const float* __restrict__ bias, float* __restrict__ C,
                       int M, int N, int K)
{
    constexpr int BK = 64;
    constexpr int WM = BM / 2, WN = BN / 2;
    constexpr int MR = WM / 16, NR = WN / 16;

    __shared__ _Float16 As[BM * BK];
    __shared__ _Float16 Bs[BN * BK];

    const int tid  = threadIdx.x;
    const int lane = tid & 63;
    const int wid  = tid >> 6;
    const int wr   = wid >> 1;
    const int wc   = wid & 1;
    const int brow = blockIdx.y * BM;
    const int bcol = blockIdx.x * BN;
    const int lr   = lane & 15;      // fragment row/col within 16
    const int kb   = lane >> 4;      // 16B chunk sub-index 0..3

    f32x4 acc[MR][NR] = {};

    for (int k0 = 0; k0 < K; k0 += BK) {
        __syncthreads();
        // stage A tile: BM*8 16B-chunks, linear LDS dest (wave-uniform base + lane*16)
#pragma unroll
        for (int i = 0; i < BM * 8; i += 256) {
            const int c = tid + i;
            const _Float16* src = A + (size_t)(brow + (c >> 3)) * K + k0 + (c & 7) * 8;
            __builtin_amdgcn_global_load_lds(
                (const __attribute__((address_space(1))) void*)src,
                (__attribute__((address_space(3))) void*)&As[(size_t)(i + wid * 64) * 8],
                16, 0, 0);
        }
        // stage B tile
#pragma unroll
        for (int i = 0; i < BN * 8; i += 256) {
            const int c = tid + i;
            const _Float16* src = Bw + (size_t)(bcol + (c >> 3)) * K + k0 + (c & 7) * 8;
            __builtin_amdgcn_global_load_lds(
                (const __attribute__((address_space(1))) void*)src,
                (__attribute__((address_space(3))) void*)&Bs[(size_t)(i + wid * 64) * 8],
                16, 0, 0);
        }
        __syncthreads();

#pragma unroll
        for (int ks = 0; ks < 2; ++ks) {
            f16x8 af[MR], bf[NR];
#pragma unroll
            for (int m = 0; m < MR; ++m) {
                const int row = wr * WM + m * 16 + lr;
                const int ch  = (ks * 4 + kb) ^ (row & 7);
                af[m] = *(const f16x8*)&As[row * BK + ch * 8];
            }
#pragma unroll
            for (int n = 0; n < NR; ++n) {
                const int row = wc * WN + n * 16 + lr;
                const int ch  = (ks * 4 + kb) ^ (row & 7);
                bf[n] = *(const f16x8*)&Bs[row * BK + ch * 8];
            }
#pragma unroll
            for (int m = 0; m < MR; ++m)
#pragma unroll
                for (int n = 0; n < NR; ++n)
                    acc[m][n] = __builtin_amdgcn_mfma_f32_16x16x32_f16(af[m], bf[n], acc[m][n], 0, 0, 0);
        }
    }

    // C/D mapping (verified round 1): col = lane&15, row = (lane>>4)*4 + j
#pragma unroll
    for (int m = 0; m < MR; ++m) {
        const int row0 = brow + wr * WM + m * 16 + (lane >> 4) * 4;
#pragma unroll
        for (int n = 0; n < NR; ++n) {
            const int col = bcol + wc * WN + n * 16 + lr;
            const float bv = bias[col];
#pragma unroll
            for (int j = 0; j < 4; ++j) {
                float v = acc[m][n][j] + bv;
                if (EPI) v = sigmoidf_(v);
                C[(size_t)(row0 + j) * N + col] = v;
            }
        }
    }
}

// ---------------------------------------------------------------------------
// GRU gate with h=0, writing h_new as fp16 in the same chunk-XOR swizzled
// layout (row = batch index) so GEMM2 can stage it via global_load_lds.
// ---------------------------------------------------------------------------
__global__ void gate_swz(const float* __restrict__ gi, const float* __restrict__ b_hh,
                         _Float16* __restrict__ hn, int B, int H)
{
    const int ch = H >> 3;
    const int c = blockIdx.x * 256 + threadIdx.x;
    if (c >= B * ch) return;
    const int b  = c / ch;
    const int hc = c - b * ch;
    const int h0 = hc * 8;
    const float* g = gi + (size_t)b * 3 * H;
    f16x8 o;
#pragma unroll
    for (int q = 0; q < 2; ++q) {
        float4 ir  = *(const float4*)(g + h0 + 4 * q);
        float4 iz  = *(const float4*)(g + H + h0 + 4 * q);
        float4 in4 = *(const float4*)(g + 2 * H + h0 + 4 * q);
        float4 hr  = *(const float4*)(b_hh + h0 + 4 * q);
        float4 hz  = *(const float4*)(b_hh + H + h0 + 4 * q);
        float4 hn4 = *(const float4*)(b_hh + 2 * H + h0 + 4 * q);
        float r, z;
        r = sigmoidf_(ir.x + hr.x); z = sigmoidf_(iz.x + hz.x);
        o[4 * q + 0] = (_Float16)((1.0f - z) * tanhf(in4.x + r * hn4.x));
        r = sigmoidf_(ir.y + hr.y); z = sigmoidf_(iz.y + hz.y);
        o[4 * q + 1] = (_Float16)((1.0f - z) * tanhf(in4.y + r * hn4.y));
        r = sigmoidf_(ir.z + hr.z); z = sigmoidf_(iz.z + hz.z);
        o[4 * q + 2] = (_Float16)((1.0f - z) * tanhf(in4.z + r * hn4.z));
        r = sigmoidf_(ir.w + hr.w); z = sigmoidf_(iz.w + hz.w);
        o[4 * q + 3] = (_Float16)((1.0f - z) * tanhf(in4.w + r * hn4.w));
    }
    const int hcs = (hc & ~7) | ((hc & 7) ^ (b & 7));
    *(f16x8*)(hn + (size_t)b * H + (size_t)hcs * 8) = o;
}

// out[b][o][t] = res[b][o], coalesced float2 stores (T even).
__global__ void bcast_kernel(const float* __restrict__ res,
                             float* __restrict__ out, int BO, int T)
{
    const int bo0 = blockIdx.x * 256;
    if (T & 1) {
        float* op = out + (size_t)bo0 * T;
        const int n = 256 * T;
        for (int j = threadIdx.x; j < n; j += blockDim.x)
            op[j] = res[bo0 + j / T];
    } else {
        const int half = T >> 1;
        float2* o2 = (float2*)(out + (size_t)bo0 * T);
        const int n2 = 256 * half;
        for (int j = threadIdx.x; j < n2; j += blockDim.x) {
            const float v = res[bo0 + j / half];
            o2[j] = make_float2(v, v);
        }
    }
}

extern "C" void kernel_launch(void* const* d_in, const int* in_sizes, int n_in,
                              void* d_out, int out_size, void* d_ws, size_t ws_size,
                              hipStream_t stream)
{
    const float* x     = (const float*)d_in[0];
    const float* w_ih  = (const float*)d_in[1];
    // d_in[2] = w_hh: dead (hidden state stays 0)
    const float* b_ih  = (const float*)d_in[3];
    const float* b_hh  = (const float*)d_in[4];
    const float* w_cls = (const float*)d_in[5];
    const float* b_cls = (const float*)d_in[6];

    const int H3 = in_sizes[3];          // 6144
    const int H  = H3 / 3;               // 2048
    const int I  = in_sizes[1] / H3;     // 2048
    const int B  = in_sizes[0] / I;      // 1024
    const int O  = in_sizes[6];          // 2048
    const int T  = out_size / (B * O);   // 30

    // ws (24 MB used): x16 | wcls16 | hnew16 | res
    _Float16* x16    = (_Float16*)d_ws;                   // B*I fp16      (4 MB)
    _Float16* wcls16 = x16 + (size_t)B * I;               // O*H fp16      (8 MB)
    _Float16* hn16   = wcls16 + (size_t)O * H;            // B*H fp16      (4 MB)
    float*    res    = (float*)(hn16 + (size_t)B * H);    // B*O fp32      (8 MB)

    // d_out doubles as scratch for the big intermediates; both are fully
    // consumed before bcast overwrites the whole output buffer.
    char*     outc  = (char*)d_out;
    _Float16* wih16 = (_Float16*)outc;                            // 3H*I fp16 (24 MB)
    float*    gi    = (float*)(outc + (size_t)H3 * I * 2);        // B*3H fp32 (24 MB)
    float*    out   = (float*)d_out;

    dim3 blk(256);

    // fp32 -> fp16 pre-swizzled conversions
    cvt_swz<<<(B * I / 8 + 255) / 256, blk, 0, stream>>>(x, x16, B * I / 8, I / 8);
    cvt_swz<<<(H3 * I / 8 + 255) / 256, blk, 0, stream>>>(w_ih, wih16, H3 * I / 8, I / 8);
    cvt_swz<<<(O * H / 8 + 255) / 256, blk, 0, stream>>>(w_cls, wcls16, O * H / 8, H / 8);

    // GEMM1: gi = x @ w_ih^T + b_ih   (M=1024, N=6144, K=2048) -> 768 blocks (3/CU)
    gemm16<64, 128, 0><<<dim3(H3 / 128, B / 64), blk, 0, stream>>>(x16, wih16, b_ih, gi, B, H3, I);

    // gate -> h_new (fp16, swizzled)
    gate_swz<<<(B * H / 8 + 255) / 256, blk, 0, stream>>>(gi, b_hh, hn16, B, H);

    // GEMM2: res = sigmoid(h_new @ w_cls^T + b_cls)  (M=1024, N=2048, K=2048) -> 512 blocks (2/CU)
    gemm16<64, 64, 1><<<dim3(O / 64, B / 64), blk, 0, stream>>>(hn16, wcls16, b_cls, res, B, O, H);

    // broadcast across T
    bcast_kernel<<<(B * O) / 256, blk, 0, stream>>>(res, out, B * O, T);
}